// Round 2
// 848.816 us; speedup vs baseline: 1.0002x; 1.0002x over previous
//
#include <hip/hip_runtime.h>
#include <hip/hip_bf16.h>

typedef short bf16x8 __attribute__((ext_vector_type(8)));
typedef float f32x4 __attribute__((ext_vector_type(4)));

__device__ __forceinline__ float relu_f(float v){ return v > 0.f ? v : 0.f; }

__device__ __forceinline__ f32x4 mfma16(bf16x8 a, bf16x8 b, f32x4 c){
  return __builtin_amdgcn_mfma_f32_16x16x32_bf16(a, b, c, 0, 0, 0);
}

__device__ __forceinline__ short bfbits(float v){
  __hip_bfloat16 h = __float2bfloat16(v);
  return *reinterpret_cast<short*>(&h);
}

// ---------- prep: all weight conversions + bottom layer 0, one kernel ----------
// blocks [0,512): bot0   (8192x13 @ 13x512^T + b, relu, fp32 -> bf16)
// blocks [512,1024): bw1 -> bf16 (256x512)
// blocks [1024,1088): bw2 -> bf16 (64x256)
// blocks [1088,1920): tw0 -> bf16 padded K 415->416
// blocks [1920,2432): tw1 -> bf16 (256x512)
__global__ __launch_bounds__(256) void prep(
    const float* __restrict__ X,  const float* __restrict__ bw0,
    const float* __restrict__ bb0, __hip_bfloat16* __restrict__ H,
    const float* __restrict__ bw1, __hip_bfloat16* __restrict__ w1b,
    const float* __restrict__ bw2, __hip_bfloat16* __restrict__ w2b,
    const float* __restrict__ tw0, __hip_bfloat16* __restrict__ tw0b,
    const float* __restrict__ tw1, __hip_bfloat16* __restrict__ tw1b){
  int blk = blockIdx.x;
  if (blk < 512){
    int n = threadIdx.x;
    int m0 = blk * 16;
    float w0[13], w1[13];
#pragma unroll
    for (int k = 0; k < 13; k++){ w0[k] = bw0[n*13 + k]; w1[k] = bw0[(n+256)*13 + k]; }
    float b0 = bb0[n], b1 = bb0[n + 256];
    for (int mi = 0; mi < 16; mi++){
      int m = m0 + mi;
      float a0 = b0, a1 = b1;
#pragma unroll
      for (int k = 0; k < 13; k++){
        float xv = X[m*13 + k];
        a0 += xv * w0[k]; a1 += xv * w1[k];
      }
      H[(size_t)m*512 + n]       = __float2bfloat16(relu_f(a0));
      H[(size_t)m*512 + n + 256] = __float2bfloat16(relu_f(a1));
    }
  } else if (blk < 1024){
    int i = (blk - 512)*256 + threadIdx.x;
    w1b[i] = __float2bfloat16(bw1[i]);
  } else if (blk < 1088){
    int i = (blk - 1024)*256 + threadIdx.x;
    w2b[i] = __float2bfloat16(bw2[i]);
  } else if (blk < 1920){
    int i = (blk - 1088)*256 + threadIdx.x;   // 512*416 = 832 blocks exactly
    int r = i / 416, k = i - r*416;
    float v = (k < 415) ? tw0[r*415 + k] : 0.f;
    tw0b[i] = __float2bfloat16(v);
  } else {
    int i = (blk - 1920)*256 + threadIdx.x;
    tw1b[i] = __float2bfloat16(tw1[i]);
  }
}

// ---------- generic MFMA GEMM: C[M,N] = relu(A[M,K] @ W[N,K]^T + bias) ----------
// compile-time K: full unroll -> compiler pipelines loads across k-iterations
template<int NT, int K>
__global__ __launch_bounds__(256) void gemm_br(const __hip_bfloat16* __restrict__ A,
    const __hip_bfloat16* __restrict__ W, const float* __restrict__ Bv,
    __hip_bfloat16* __restrict__ C, int N, int ldc){
  int lane = threadIdx.x & 63;
  int wave = blockIdx.x * 4 + (threadIdx.x >> 6);
  int ntiles = N / (16 * NT);
  int mi = wave / ntiles, ni = wave % ntiles;
  int row = lane & 15, quad = lane >> 4;
  const __hip_bfloat16* Ap = A + (size_t)(mi*16 + row) * K + quad*8;
  const __hip_bfloat16* Wp = W + (size_t)(ni*16*NT + row) * K + quad*8;
  f32x4 acc[NT];
#pragma unroll
  for (int t = 0; t < NT; t++) acc[t] = (f32x4){0.f, 0.f, 0.f, 0.f};
#pragma unroll
  for (int k = 0; k < K; k += 32){
    bf16x8 a = *(const bf16x8*)(Ap + k);
#pragma unroll
    for (int t = 0; t < NT; t++){
      bf16x8 b = *(const bf16x8*)(Wp + (size_t)t*16*K + k);
      acc[t] = mfma16(a, b, acc[t]);
    }
  }
#pragma unroll
  for (int t = 0; t < NT; t++){
    int n = ni*16*NT + t*16 + row;
    float bn = Bv[n];
#pragma unroll
    for (int r = 0; r < 4; r++){
      int m = mi*16 + quad*4 + r;
      C[(size_t)m*ldc + n] = __float2bfloat16(relu_f(acc[t][r] + bn));
    }
  }
}

// ---------- fused embedding gather/mean + interaction ----------
// one wave per sample. Gather phase: for each of the 26 tables, the 4 looked-up
// rows are each fetched by the FULL wave in one coalesced 256B instruction
// (lane = element index), summed, and the fp32 mean parked in padded LDS
// ly[t][64(+4 pad)]. Interaction phase: identical fragment/lane layout and MFMA
// sequence as the previously verified kernel, with fragments sourced from LDS
// (bit-identical values: same fp32 sum order, same *0.25f, same bf16 convert).
__global__ __launch_bounds__(256) void embint(const int* __restrict__ I,
    const float* __restrict__ T, __hip_bfloat16* __restrict__ R){
  __shared__ __align__(16) float ly[4][26][68];   // 28.3 KB; stride 68 -> 2-way banks (free)
  int wv   = threadIdx.x >> 6;
  int lane = threadIdx.x & 63;
  int b    = blockIdx.x * 4 + wv;
  float (*L)[68] = ly[wv];

  // lane t (t<26) holds the 4 indices for table t of this sample
  int4 myix = (int4){0,0,0,0};
  if (lane < 26) myix = *(const int4*)(I + ((size_t)lane << 15) + (b << 2));

#pragma unroll
  for (int t = 0; t < 26; t++){
    // broadcast table-t indices to scalar regs (uniform addressing)
    int i0 = __builtin_amdgcn_readlane(myix.x, t);
    int i1 = __builtin_amdgcn_readlane(myix.y, t);
    int i2 = __builtin_amdgcn_readlane(myix.z, t);
    int i3 = __builtin_amdgcn_readlane(myix.w, t);
    const float* tb = T + (size_t)t * 6400064ull + lane;   // 100001*64
    // one 256B fully-coalesced load per row; 4 independent rows in flight
    float s0 = tb[(size_t)(unsigned)i0 * 64];
    float s1 = tb[(size_t)(unsigned)i1 * 64];
    float s2 = tb[(size_t)(unsigned)i2 * 64];
    float s3 = tb[(size_t)(unsigned)i3 * 64];
    L[t][lane] = (((s0 + s1) + s2) + s3) * 0.25f;   // same order as before
  }
  __syncthreads();

  int row = lane & 15, quad = lane >> 4;
  __hip_bfloat16* Rb = R + (size_t)b * 416;

  f32x4 a00 = {0,0,0,0}, a10 = {0,0,0,0}, a11 = {0,0,0,0};
#pragma unroll
  for (int k = 0; k < 64; k += 32){
    int ko = k + quad*8;
    bf16x8 f0, f1 = {0,0,0,0,0,0,0,0};
    if (row == 0){
      f0 = *(const bf16x8*)(Rb + ko);
    } else {
      const float* p = L[row - 1] + ko;
#pragma unroll
      for (int j = 0; j < 8; j++) f0[j] = bfbits(p[j]);
    }
    if (row < 11){
      const float* p = L[row + 15] + ko;
#pragma unroll
      for (int j = 0; j < 8; j++) f1[j] = bfbits(p[j]);
    }
    a00 = mfma16(f0, f0, a00);
    a10 = mfma16(f1, f0, a10);
    a11 = mfma16(f1, f1, a11);
  }
#pragma unroll
  for (int r = 0; r < 4; r++){
    { int i = quad*4 + r, j = row;
      if (i > j) Rb[64 + i*(i-1)/2 + j] = __float2bfloat16(a00[r]); }
    { int i = 16 + quad*4 + r, j = row;
      if (i < 27) Rb[64 + i*(i-1)/2 + j] = __float2bfloat16(a10[r]); }
    { int i = 16 + quad*4 + r, j = 16 + row;
      if (i < 27 && i > j) Rb[64 + i*(i-1)/2 + j] = __float2bfloat16(a11[r]); }
  }
  if (lane == 0) Rb[415] = __float2bfloat16(0.f);
}

// ---------- fused top L1 gemm + final dot ----------
// block = 16 rows; wave w handles cols [w*64, w*64+64); epilogue folds
// relu(h+b) * w2 and reduces to out[m] without materializing h4.
template<int K>
__global__ __launch_bounds__(256) void top12(const __hip_bfloat16* __restrict__ A,
    const __hip_bfloat16* __restrict__ W, const float* __restrict__ Bv,
    const float* __restrict__ W2, const float* __restrict__ b2,
    float* __restrict__ O){
  __shared__ float part[4][16];
  int lane = threadIdx.x & 63, wv = threadIdx.x >> 6;
  int mi = blockIdx.x;
  int row = lane & 15, quad = lane >> 4;
  const __hip_bfloat16* Ap = A + (size_t)(mi*16 + row) * K + quad*8;
  int nb = wv * 64;
  const __hip_bfloat16* Wp = W + (size_t)(nb + row) * K + quad*8;
  f32x4 acc[4];
#pragma unroll
  for (int t = 0; t < 4; t++) acc[t] = (f32x4){0.f, 0.f, 0.f, 0.f};
#pragma unroll
  for (int k = 0; k < K; k += 32){
    bf16x8 a = *(const bf16x8*)(Ap + k);
#pragma unroll
    for (int t = 0; t < 4; t++){
      bf16x8 b = *(const bf16x8*)(Wp + (size_t)t*16*K + k);
      acc[t] = mfma16(a, b, acc[t]);
    }
  }
  float p[4];
#pragma unroll
  for (int r = 0; r < 4; r++){
    float s = 0.f;
#pragma unroll
    for (int t = 0; t < 4; t++){
      int n = nb + t*16 + row;
      s += relu_f(acc[t][r] + Bv[n]) * W2[n];
    }
    p[r] = s;
  }
#pragma unroll
  for (int r = 0; r < 4; r++){
#pragma unroll
    for (int o = 1; o < 16; o <<= 1) p[r] += __shfl_xor(p[r], o, 64);
  }
  if (row == 0){
#pragma unroll
    for (int r = 0; r < 4; r++) part[wv][quad*4 + r] = p[r];
  }
  __syncthreads();
  if (threadIdx.x < 16){
    float s = part[0][threadIdx.x] + part[1][threadIdx.x]
            + part[2][threadIdx.x] + part[3][threadIdx.x] + b2[0];
    O[mi*16 + threadIdx.x] = s;
  }
}

extern "C" void kernel_launch(void* const* d_in, const int* in_sizes, int n_in,
                              void* d_out, int out_size, void* d_ws, size_t ws_size,
                              hipStream_t stream) {
  const float* dense_x = (const float*)d_in[0];
  const int*   lS_i    = (const int*)d_in[2];
  const float* tables  = (const float*)d_in[3];
  const float* bw0 = (const float*)d_in[4];  const float* bb0 = (const float*)d_in[5];
  const float* bw1 = (const float*)d_in[6];  const float* bb1 = (const float*)d_in[7];
  const float* bw2 = (const float*)d_in[8];  const float* bb2 = (const float*)d_in[9];
  const float* tw0 = (const float*)d_in[10]; const float* tb0 = (const float*)d_in[11];
  const float* tw1 = (const float*)d_in[12]; const float* tb1 = (const float*)d_in[13];
  const float* tw2 = (const float*)d_in[14]; const float* tb2 = (const float*)d_in[15];
  float* out = (float*)d_out;
  char* ws = (char*)d_ws;

  // workspace layout (bytes), 16B aligned
  __hip_bfloat16* w1b  = (__hip_bfloat16*)(ws + 0);         // 256*512*2
  __hip_bfloat16* w2b  = (__hip_bfloat16*)(ws + 262144);    // 64*256*2
  __hip_bfloat16* tw0b = (__hip_bfloat16*)(ws + 294912);    // 512*416*2
  __hip_bfloat16* tw1b = (__hip_bfloat16*)(ws + 720896);    // 256*512*2
  __hip_bfloat16* h0   = (__hip_bfloat16*)(ws + 983040);    // 8192*512*2
  __hip_bfloat16* h1   = (__hip_bfloat16*)(ws + 9371648);   // 8192*256*2
  __hip_bfloat16* R    = (__hip_bfloat16*)(ws + 13565952);  // 8192*416*2
  __hip_bfloat16* h3   = h0;  // h0 dead after bot L1

  // 1. all weight conversions + bottom L0
  prep<<<2432, 256, 0, stream>>>(dense_x, bw0, bb0, h0,
                                 bw1, w1b, bw2, w2b, tw0, tw0b, tw1, tw1b);
  // 2. bottom L1: M=8192 N=256 K=512 -> h1
  gemm_br<4,512><<<512, 256, 0, stream>>>(h0, w1b, bb1, h1, 256, 256);
  // 3. bottom L2: M=8192 N=64 K=256 -> x into R[:, :64] (ldc=416)
  gemm_br<1,256><<<512, 256, 0, stream>>>(h1, w2b, bb2, R, 64, 416);
  // 4. fused embedding + interaction -> R[:, 64:415], pad R[:,415]=0
  embint<<<8192/4, 256, 0, stream>>>(lS_i, tables, R);
  // 5. top L0: M=8192 N=512 K=416 -> h3
  gemm_br<4,416><<<1024, 256, 0, stream>>>(R, tw0b, tb0, h3, 512, 512);
  // 6. top L1 + final dot -> out
  top12<512><<<512, 256, 0, stream>>>(h3, tw1b, tb1, tw2, tb2, out);

  (void)in_sizes; (void)n_in; (void)out_size; (void)ws_size;
}